// Round 5
// baseline (1295.250 us; speedup 1.0000x reference)
//
#include <hip/hip_runtime.h>
#include <math.h>

typedef float floatx4 __attribute__((ext_vector_type(4)));
typedef __bf16 bf16x8 __attribute__((ext_vector_type(8)));
typedef unsigned short u16;

#define LDK 72  // LDS row stride in ushorts for fattn (144B, 16B-aligned)

__device__ inline u16 to_bf16(float f) {
  union { float f; unsigned u; } v; v.f = f;
  unsigned u = v.u;
  u += 0x7FFFu + ((u >> 16) & 1u);
  return (u16)(u >> 16);
}
__device__ inline float bf2f(u16 h) {
  union { unsigned u; float f; } v; v.u = ((unsigned)h) << 16; return v.f;
}

// async global->LDS, 16B per lane. LDS dest must be wave-uniform base
// (HW adds lane*16). Swizzled LDS content achieved by pre-swizzling the
// per-lane GLOBAL source address (rule #21: both-sides-or-neither).
__device__ inline void gload16(const void* g, void* l) {
  __builtin_amdgcn_global_load_lds(
      (const __attribute__((address_space(1))) unsigned int*)g,
      (__attribute__((address_space(3))) unsigned int*)l, 16, 0, 0);
}

struct GemmArgs {
  const void* A; const void* B; void* C; void* C2;
  int lda, ldb, ldc, N, Kc;   // N = nsplit for amode=2
  long sA1, sA2, sB1, sB2, sC1, sC2;
  float alpha;
  const float* bias; int biasz;   // bias index = col + zi*biasz
  const float* res; int ldres;
  const float* aml;  // amode=2/9: ml buffer [ns][2048][8][2]
  const float* lng; const float* lnb;  // amode=3: layernorm gamma/beta
  int amode;   // 1: A bf16, 2: A = flash-split combine, 3: A = layernorm(fp32 A),
               // 9: loss
  int cmode;   // 0: fp32 C, 1: bf16 C, 2: bf16 C transposed,
               // 4: dual write fp32 C + bf16 C2
  int act;     // exact gelu
  int smode;   // shifted bf16 scatter: C[row][col+row-511] = bf16(v) if >=0
  int bdiv, kparts;
  int gx, gy;  // grid decomposition of this descriptor's block range
};

#define MAXG 10
struct GemmBatch {
  GemmArgs g[MAXG];
  int end[MAXG];   // cumulative block-count ends
  int ng;
};

// Grouped GEMM, 64x64 tile, K-step 64 + loss descriptor mode.
// XCD chunk swizzle: consecutive LOGICAL blocks (which share A panels) are
// given to the SAME XCD (hw round-robins %8) -> A fetched ~once/XCD.
__global__ __launch_bounds__(256) void gemmb_k(GemmBatch gb) {
  int nwg = gridDim.x;
  int hw = blockIdx.x;
  int qn = nwg >> 3, rn = nwg & 7;
  int xcd = hw & 7, ii = hw >> 3;
  int bid = (xcd < rn ? xcd * (qn + 1) : rn * (qn + 1) + (xcd - rn) * qn) + ii;

  int gi = 0;
  while (bid >= gb.end[gi]) ++gi;
  const GemmArgs g = gb.g[gi];
  int lb = bid - (gi ? gb.end[gi - 1] : 0);
  int tid = threadIdx.x;

  if (g.amode == 9) {  // MSE loss with fused 2-way flash combine
    const float* oc = (const float*)g.A;
    const float* Op = (const float*)g.B;
    const float* ml = g.aml;
    float s = 0.f;
    for (long i = (long)lb * 256 + tid; i < 1048576; i += 256L * g.gx) {
      int row = (int)(i >> 9), col = (int)(i & 511), h = col >> 6;
      const float* mlp = ml + ((long)row * 8 + h) * 2;
      float m0v = mlp[0], l0v = mlp[1];
      float m1v = mlp[32768], l1v = mlp[32769];
      float mm = fmaxf(m0v, m1v);
      float w0 = __expf(m0v - mm), w1 = __expf(m1v - mm);
      float ov = (w0 * Op[i] + w1 * Op[1048576 + i]) / (w0 * l0v + w1 * l1v);
      float d = oc[i] - ov; s += d * d;
    }
    for (int o = 32; o > 0; o >>= 1) s += __shfl_xor(s, o, 64);
    __shared__ float red[4];
    if ((tid & 63) == 0) red[tid >> 6] = s;
    __syncthreads();
    if (tid == 0) atomicAdd((float*)g.C, red[0] + red[1] + red[2] + red[3]);
    return;
  }

  int bx = lb % g.gx;
  int rem = lb / g.gx;
  int by = rem % g.gy;
  int z = rem / g.gy;

  int kp = z % g.kparts;
  int zz = z / g.kparts;
  int zi = zz / g.bdiv, zj = zz % g.bdiv;
  long aoff = (long)zi * g.sA1 + (long)zj * g.sA2;
  long boff = (long)zi * g.sB1 + (long)zj * g.sB2;
  long coff = (long)zi * g.sC1 + (long)zj * g.sC2;
  const float* Af = (const float*)g.A + aoff;
  const u16* Ah = (const u16*)g.A + aoff;
  const u16* Bh = (const u16*)g.B + boff;

  int m0 = by * 64, n0 = bx * 64;
  __shared__ u16 As[64][64];
  __shared__ u16 Bs[64][64];
  char* Asb = (char*)&As[0][0];
  char* Bsb = (char*)&Bs[0][0];
  int wave = tid >> 6, lane = tid & 63;
  int wr = (wave >> 1) * 32, wc = (wave & 1) * 32;
  int lr = lane & 15, qrow = lane >> 4;

  // async-staging geometry: lane covers LDS bytes o (linear); its global
  // source is the logical element whose swizzle lands at o.
  unsigned o0 = wave * 1024u + lane * 16u;
  unsigned o1 = o0 + 4096u;
  int ga_r0 = o0 >> 7, ga_r1 = o1 >> 7;
  int ga_c0 = (int)(o0 & 127u) ^ ((ga_r0 & 7) << 4);
  int ga_c1 = (int)(o1 & 127u) ^ ((ga_r1 & 7) << 4);
  long ldaB = (long)g.lda * 2, ldbB = (long)g.ldb * 2;
  // reg-staging geometry
  int r = tid >> 2, c16 = (tid & 3) << 4;
  int sw0 = (r << 7) + (((tid & 3) << 5) ^ ((r & 7) << 4));
  int sw1 = (r << 7) + ((((tid & 3) << 5) + 16) ^ ((r & 7) << 4));

  // amode=3: per-row LN stats, register-resident (pre-pass thread r == staging
  // thread r, so no LDS handoff needed). Two-pass variance == layernorm_k.
  float lnmu = 0.f, lnrs = 0.f;
  if (g.amode == 3) {
    const float* rp = Af + (long)(m0 + r) * g.lda + (tid & 3) * 128;
    float s = 0.f;
    for (int j = 0; j < 128; j += 4) {
      float4 v = *(const float4*)(rp + j);
      s += v.x + v.y + v.z + v.w;
    }
    s += __shfl_xor(s, 1, 64); s += __shfl_xor(s, 2, 64);
    lnmu = s * (1.f / 512.f);
    float ss = 0.f;
    for (int j = 0; j < 128; j += 4) {
      float4 v = *(const float4*)(rp + j);
      float d0 = v.x - lnmu, d1 = v.y - lnmu, d2 = v.z - lnmu, d3 = v.w - lnmu;
      ss += d0 * d0 + d1 * d1 + d2 * d2 + d3 * d3;
    }
    ss += __shfl_xor(ss, 1, 64); ss += __shfl_xor(ss, 2, 64);
    lnrs = rsqrtf(ss * (1.f / 512.f) + 1e-5f);
  }

  floatx4 acc[2][2];
#pragma unroll
  for (int i = 0; i < 2; ++i)
#pragma unroll
    for (int j = 0; j < 2; ++j)
#pragma unroll
      for (int rr = 0; rr < 4; ++rr) acc[i][j][rr] = 0.f;

  int kb0 = kp * g.Kc, kb1 = kb0 + g.Kc;
  for (int k0 = kb0; k0 < kb1; k0 += 64) {
    if (g.amode == 1) {
      const char* Ab = (const char*)Ah + ((long)m0 * g.lda + k0) * 2;
      gload16(Ab + ga_r0 * ldaB + ga_c0, Asb + wave * 1024);
      gload16(Ab + ga_r1 * ldaB + ga_c1, Asb + 4096 + wave * 1024);
    } else if (g.amode == 3) {  // A = layernorm(fp32 rows) -> bf16
      const float* ap = Af + (long)(m0 + r) * g.lda + k0 + c16;
      const float* gp = g.lng + k0 + c16;
      const float* bp = g.lnb + k0 + c16;
      float4 a0 = *(const float4*)ap, a1 = *(const float4*)(ap + 4);
      float4 a2 = *(const float4*)(ap + 8), a3 = *(const float4*)(ap + 12);
      float4 g0 = *(const float4*)gp, g1 = *(const float4*)(gp + 4);
      float4 g2 = *(const float4*)(gp + 8), g3 = *(const float4*)(gp + 12);
      float4 b0 = *(const float4*)bp, b1 = *(const float4*)(bp + 4);
      float4 b2v = *(const float4*)(bp + 8), b3 = *(const float4*)(bp + 12);
      union { u16 s[8]; uint4 v; } u0, u1;
      u0.s[0] = to_bf16((a0.x - lnmu) * lnrs * g0.x + b0.x);
      u0.s[1] = to_bf16((a0.y - lnmu) * lnrs * g0.y + b0.y);
      u0.s[2] = to_bf16((a0.z - lnmu) * lnrs * g0.z + b0.z);
      u0.s[3] = to_bf16((a0.w - lnmu) * lnrs * g0.w + b0.w);
      u0.s[4] = to_bf16((a1.x - lnmu) * lnrs * g1.x + b1.x);
      u0.s[5] = to_bf16((a1.y - lnmu) * lnrs * g1.y + b1.y);
      u0.s[6] = to_bf16((a1.z - lnmu) * lnrs * g1.z + b1.z);
      u0.s[7] = to_bf16((a1.w - lnmu) * lnrs * g1.w + b1.w);
      u1.s[0] = to_bf16((a2.x - lnmu) * lnrs * g2.x + b2v.x);
      u1.s[1] = to_bf16((a2.y - lnmu) * lnrs * g2.y + b2v.y);
      u1.s[2] = to_bf16((a2.z - lnmu) * lnrs * g2.z + b2v.z);
      u1.s[3] = to_bf16((a2.w - lnmu) * lnrs * g2.w + b2v.w);
      u1.s[4] = to_bf16((a3.x - lnmu) * lnrs * g3.x + b3.x);
      u1.s[5] = to_bf16((a3.y - lnmu) * lnrs * g3.y + b3.y);
      u1.s[6] = to_bf16((a3.z - lnmu) * lnrs * g3.z + b3.z);
      u1.s[7] = to_bf16((a3.w - lnmu) * lnrs * g3.w + b3.w);
      *(uint4*)(Asb + sw0) = u0.v; *(uint4*)(Asb + sw1) = u1.v;
    } else {  // amode 2: A = combine of g.N flash splits (ex-fcomb, fused)
      int row = m0 + r;
      int k = k0 + c16;               // all 16 cols in one head (k0%64==0)
      int ns = g.N;
      const float* mlp = g.aml + ((long)row * 8 + (k >> 6)) * 2;
      float mm = -1e30f;
#pragma unroll 3
      for (int s = 0; s < 3; ++s)
        if (s < ns) mm = fmaxf(mm, mlp[s * 32768]);
      float wgt[3]; float den = 0.f;
#pragma unroll 3
      for (int s = 0; s < 3; ++s)
        if (s < ns) { wgt[s] = __expf(mlp[s * 32768] - mm); den += wgt[s] * mlp[s * 32768 + 1]; }
      float inv = 1.f / den;
      float a16[16];
#pragma unroll
      for (int j = 0; j < 16; ++j) a16[j] = 0.f;
      const float* p0 = (const float*)g.A + (long)row * g.lda + k;
#pragma unroll 3
      for (int s = 0; s < 3; ++s)
        if (s < ns) {
          float w = wgt[s] * inv;
          const float* p = p0 + (long)s * g.sA1;
#pragma unroll
          for (int j = 0; j < 4; ++j) {
            float4 xx = *(const float4*)(p + j * 4);
            a16[j * 4 + 0] += w * xx.x; a16[j * 4 + 1] += w * xx.y;
            a16[j * 4 + 2] += w * xx.z; a16[j * 4 + 3] += w * xx.w;
          }
        }
      union { u16 s[8]; uint4 v; } u0, u1;
#pragma unroll
      for (int j = 0; j < 8; ++j) u0.s[j] = to_bf16(a16[j]);
#pragma unroll
      for (int j = 0; j < 8; ++j) u1.s[j] = to_bf16(a16[8 + j]);
      *(uint4*)(Asb + sw0) = u0.v; *(uint4*)(Asb + sw1) = u1.v;
    }
    {
      const char* Bb = (const char*)Bh + ((long)n0 * g.ldb + k0) * 2;
      gload16(Bb + ga_r0 * ldbB + ga_c0, Bsb + wave * 1024);
      gload16(Bb + ga_r1 * ldbB + ga_c1, Bsb + 4096 + wave * 1024);
    }
    __syncthreads();   // drains vmcnt (gload) + lgkm (ds_write)
#pragma unroll
    for (int ks = 0; ks < 2; ++ks) {
      int xk = ((ks * 32 + qrow * 8) << 1) ^ ((lr & 7) << 4);
      int rA0 = wr + lr, rB0 = wc + lr;
      bf16x8 a0 = *(const bf16x8*)(Asb + (rA0 << 7) + xk);
      bf16x8 a1 = *(const bf16x8*)(Asb + ((rA0 + 16) << 7) + xk);
      bf16x8 b0 = *(const bf16x8*)(Bsb + (rB0 << 7) + xk);
      bf16x8 b1 = *(const bf16x8*)(Bsb + ((rB0 + 16) << 7) + xk);
      acc[0][0] = __builtin_amdgcn_mfma_f32_16x16x32_bf16(a0, b0, acc[0][0], 0, 0, 0);
      acc[0][1] = __builtin_amdgcn_mfma_f32_16x16x32_bf16(a0, b1, acc[0][1], 0, 0, 0);
      acc[1][0] = __builtin_amdgcn_mfma_f32_16x16x32_bf16(a1, b0, acc[1][0], 0, 0, 0);
      acc[1][1] = __builtin_amdgcn_mfma_f32_16x16x32_bf16(a1, b1, acc[1][1], 0, 0, 0);
    }
    __syncthreads();
  }

#pragma unroll
  for (int mt = 0; mt < 2; ++mt)
#pragma unroll
    for (int nt = 0; nt < 2; ++nt) {
      int row0 = m0 + wr + mt * 16 + qrow * 4;
      int col = n0 + wc + nt * 16 + lr;
      if (g.cmode == 2) {
        ushort4 o;
        o.x = to_bf16(acc[mt][nt][0] * g.alpha);
        o.y = to_bf16(acc[mt][nt][1] * g.alpha);
        o.z = to_bf16(acc[mt][nt][2] * g.alpha);
        o.w = to_bf16(acc[mt][nt][3] * g.alpha);
        *(ushort4*)((u16*)g.C + coff + (long)col * g.ldc + row0) = o;
      } else {
#pragma unroll
        for (int rr = 0; rr < 4; ++rr) {
          int row = row0 + rr;
          float v = acc[mt][nt][rr] * g.alpha;
          if (g.smode) {
            int oc = col + row - 511;
            if (oc >= 0) ((u16*)g.C + coff)[(long)row * g.ldc + oc] = to_bf16(v);
          } else {
            if (g.bias) v += g.bias[col + zi * g.biasz];
            if (g.res) v += g.res[(long)row * g.ldres + col];
            if (g.act) v = 0.5f * v * (1.0f + erff(v * 0.70710678118654752f));
            if (g.cmode == 1) ((u16*)g.C + coff)[(long)row * g.ldc + col] = to_bf16(v);
            else if (g.cmode == 4) {
              ((float*)g.C + coff)[(long)row * g.ldc + col] = v;
              ((u16*)g.C2 + coff)[(long)row * g.ldc + col] = to_bf16(v);
            } else ((float*)g.C + coff)[(long)row * g.ldc + col] = v;
          }
        }
      }
    }
}

struct FAttnArgs {
  const u16* Q; const u16* K; const u16* V; const u16* QP;  // QP = pre-shifted SQP
  void* O; float* Opart; float* ml;
  int L, nsplit; long sKb, sVb; int ldV;
  float scale; int obf16;
};

struct FBatch {
  FAttnArgs a[3];
  int zend[3];  // cumulative z ends
  int nf;
};

// Fused flash attention, double-buffered K/V, optional pre-shifted pos bias,
// optional KV-split (unnormalized partials + m/l; combine fused in consumers).
__global__ __launch_bounds__(256) void fattnb_k(FBatch fb) {
  int zg = blockIdx.z;
  int fi = 0;
  while (zg >= fb.zend[fi]) ++fi;
  const FAttnArgs a = fb.a[fi];
  int zl = zg - (fi ? fb.zend[fi - 1] : 0);

  int qt = blockIdx.x, h = blockIdx.y;
  int b = zl / a.nsplit, sp = zl % a.nsplit;
  int Lc = a.L / a.nsplit, kt0 = sp * Lc, T = Lc >> 6;
  int tid = threadIdx.x, wave = tid >> 6, lane = tid & 63;
  int lr = lane & 15, quad = lane >> 4;
  __shared__ u16 Qs[64][LDK];
  __shared__ u16 Ks[2][64][LDK];
  __shared__ u16 Vs[2][64][LDK];
  __shared__ u16 Qp[4][16][LDK];
  __shared__ u16 Ps[4][16][LDK];
  int r = tid >> 2, c = (tid & 3) << 4;
  {
    const u16* qp = a.Q + (long)(b * 512 + qt * 64 + r) * 512 + h * 64 + c;
    *(uint4*)&Qs[r][c] = *(const uint4*)qp;
    *(uint4*)&Qs[r][c + 8] = *(const uint4*)(qp + 8);
  }
  const u16* Kb = a.K + (long)b * a.sKb + h * 64;
  const u16* Vb = a.V + (long)b * a.sVb + (long)(h * 64) * a.ldV;
  int qrow16 = lane >> 2, qc = (lane & 3) << 4;  // wave-private SQP tile loader
  const u16* QPr = a.QP ? a.QP + ((long)b * 8 + h) * 589824 +
                          (long)(qt * 64 + wave * 16 + qrow16) * 1152 : nullptr;
  // preload tile 0 straight into LDS buffer 0
  {
    const u16* kp = Kb + (long)(kt0 + r) * 512 + c;
    *(uint4*)&Ks[0][r][c] = *(const uint4*)kp;
    *(uint4*)&Ks[0][r][c + 8] = *(const uint4*)(kp + 8);
    const u16* vp = Vb + (long)r * a.ldV + kt0 + c;
    *(uint4*)&Vs[0][r][c] = *(const uint4*)vp;
    *(uint4*)&Vs[0][r][c + 8] = *(const uint4*)(vp + 8);
  }
  uint4 qpr0, qpr1;
  if (QPr) {  // 16 u16 per lane: two uint4s
    qpr0 = *(const uint4*)(QPr + kt0 + qc);
    qpr1 = *(const uint4*)(QPr + kt0 + qc + 8);
  }

  float m_run[4], l_run[4];
  floatx4 oacc[4];
#pragma unroll
  for (int i = 0; i < 4; ++i) {
    m_run[i] = -1e30f; l_run[i] = 0.f;
#pragma unroll
    for (int j = 0; j < 4; ++j) oacc[i][j] = 0.f;
  }

  for (int t = 0; t < T; ++t) {
    int cur = t & 1;
    bool more = (t + 1) < T;
    __syncthreads();
    uint4 pk0, pk1, pv0, pv1;
    if (more) {
      int kt = kt0 + (t + 1) * 64;
      const u16* kp = Kb + (long)(kt + r) * 512 + c;
      pk0 = *(const uint4*)kp; pk1 = *(const uint4*)(kp + 8);
      const u16* vp = Vb + (long)r * a.ldV + kt + c;
      pv0 = *(const uint4*)vp; pv1 = *(const uint4*)(vp + 8);
    }
    floatx4 sacc[4];
#pragma unroll
    for (int nt = 0; nt < 4; ++nt)
#pragma unroll
      for (int j = 0; j < 4; ++j) sacc[nt][j] = 0.f;
#pragma unroll
    for (int ks = 0; ks < 2; ++ks) {
      int kq = ks * 32 + quad * 8;
      bf16x8 av = *(const bf16x8*)&Qs[wave * 16 + lr][kq];
#pragma unroll
      for (int nt = 0; nt < 4; ++nt) {
        bf16x8 bb = *(const bf16x8*)&Ks[cur][nt * 16 + lr][kq];
        sacc[nt] = __builtin_amdgcn_mfma_f32_16x16x32_bf16(av, bb, sacc[nt], 0, 0, 0);
      }
    }
    if (QPr) {
      *(uint4*)&Qp[wave][qrow16][qc] = qpr0;
      *(uint4*)&Qp[wave][qrow16][qc + 8] = qpr1;
#pragma unroll
      for (int nt = 0; nt < 4; ++nt)
#pragma unroll
        for (int rr = 0; rr < 4; ++rr)
          sacc[nt][rr] = sacc[nt][rr] * a.scale + bf2f(Qp[wave][quad * 4 + rr][nt * 16 + lr]);
      if (more) {
        qpr0 = *(const uint4*)(QPr + kt0 + (t + 1) * 64 + qc);
        qpr1 = *(const uint4*)(QPr + kt0 + (t + 1) * 64 + qc + 8);
      }
    } else {
#pragma unroll
      for (int nt = 0; nt < 4; ++nt)
#pragma unroll
        for (int rr = 0; rr < 4; ++rr) sacc[nt][rr] *= a.scale;
    }
    // online softmax (rows replicated across the 16 lanes of a quad)
#pragma unroll
    for (int rr = 0; rr < 4; ++rr) {
      float m = -1e30f;
#pragma unroll
      for (int nt = 0; nt < 4; ++nt) m = fmaxf(m, sacc[nt][rr]);
      for (int o = 8; o > 0; o >>= 1) m = fmaxf(m, __shfl_xor(m, o, 64));
      float mn = fmaxf(m_run[rr], m);
      float al = __expf(m_run[rr] - mn);
      m_run[rr] = mn;
      float s = 0.f;
#pragma unroll
      for (int nt = 0; nt < 4; ++nt) {
        float p = __expf(sacc[nt][rr] - mn);
        sacc[nt][rr] = p;
        s += p;
      }
      for (int o = 8; o > 0; o >>= 1) s += __shfl_xor(s, o, 64);
      l_run[rr] = l_run[rr] * al + s;
#pragma unroll
      for (int nt = 0; nt < 4; ++nt) oacc[nt][rr] *= al;
    }
    // P (C-layout) -> LDS -> A-layout (wave-private)
#pragma unroll
    for (int nt = 0; nt < 4; ++nt) {
      Ps[wave][quad * 4 + 0][nt * 16 + lr] = to_bf16(sacc[nt][0]);
      Ps[wave][quad * 4 + 1][nt * 16 + lr] = to_bf16(sacc[nt][1]);
      Ps[wave][quad * 4 + 2][nt * 16 + lr] = to_bf16(sacc[nt][2]);
      Ps[wave][quad * 4 + 3][nt * 16 + lr] = to_bf16(sacc[nt][3]);
    }
#pragma unroll
    for (int ks = 0; ks < 2; ++ks) {
      int kq = ks * 32 + quad * 8;
      bf16x8 av = *(const bf16x8*)&Ps[wave][lr][kq];
#pragma unroll
      for (int nt = 0; nt < 4; ++nt) {
        bf16x8 bb = *(const bf16x8*)&Vs[cur][nt * 16 + lr][kq];
        oacc[nt] = __builtin_amdgcn_mfma_f32_16x16x32_bf16(av, bb, oacc[nt], 0, 0, 0);
      }
    }
    if (more) {  // stage prefetched tile into the other buffer
      *(uint4*)&Ks[cur ^ 1][r][c] = pk0; *(uint4*)&Ks[cur ^ 1][r][c + 8] = pk1;
      *(uint4*)&Vs[cur ^ 1][r][c] = pv0; *(uint4*)&Vs[cur ^ 1][r][c + 8] = pv1;
    }
  }
  if (a.nsplit == 1) {
    float inv[4];
#pragma unroll
    for (int rr = 0; rr < 4; ++rr) inv[rr] = 1.f / l_run[rr];
#pragma unroll
    for (int nt = 0; nt < 4; ++nt)
#pragma unroll
      for (int rr = 0; rr < 4; ++rr) {
        long row = b * 512 + qt * 64 + wave * 16 + quad * 4 + rr;
        float v = oacc[nt][rr] * inv[rr];
        if (a.obf16) ((u16*)a.O)[row * 512 + h * 64 + nt * 16 + lr] = to_bf16(v);
        else ((float*)a.O)[row * 512 + h * 64 + nt * 16 + lr] = v;
      }
  } else {
#pragma unroll
    for (int nt = 0; nt < 4; ++nt)
#pragma unroll
      for (int rr = 0; rr < 4; ++rr) {
        long row = b * 512 + qt * 64 + wave * 16 + quad * 4 + rr;
        a.Opart[((long)sp * 2048 + row) * 512 + h * 64 + nt * 16 + lr] = oacc[nt][rr];
      }
    if (lr == 0)
#pragma unroll
      for (int rr = 0; rr < 4; ++rr) {
        long row = b * 512 + qt * 64 + wave * 16 + quad * 4 + rr;
        long mi = (((long)sp * 2048 + row) * 8 + h) * 2;
        a.ml[mi] = m_run[rr]; a.ml[mi + 1] = l_run[rr];
      }
  }
}

// One-shot prep: embed (dual fp32+bf16), weight transposes, conv-w pack,
// fp32->bf16 cvts, zero-fills — vectorized, one launch.
struct PrepArgs { const void* a; const void* b; void* c; void* d; int mode, p0, p1, gx, gy; };
struct PrepBatch { PrepArgs p[12]; int end[12]; int np; };

__global__ __launch_bounds__(256) void prep_k(PrepBatch pb) {
  int bid = blockIdx.x, gi = 0;
  while (bid >= pb.end[gi]) ++gi;
  PrepArgs p = pb.p[gi];
  int lb = bid - (gi ? pb.end[gi - 1] : 0);
  int tid = threadIdx.x;
  __shared__ float ls[2048];
  if (p.mode == 0) {          // embed lookup, dual write fp32 + bf16, vec4
    int i = (lb * 256 + tid) * 4;
    int row = i >> 9, d = i & 511;
    float4 v = *(const float4*)((const float*)p.a +
                                (long)((const int*)p.b)[row] * 512 + d);
    *(float4*)((float*)p.c + i) = v;
    ushort4 h;
    h.x = to_bf16(v.x); h.y = to_bf16(v.y); h.z = to_bf16(v.z); h.w = to_bf16(v.w);
    *(ushort4*)((u16*)p.d + i) = h;
  } else if (p.mode == 1) {   // fp32 [K][N] -> bf16 [N][K] transpose, vec store
    int K = p.p0, N = p.p1;
    int bx = lb % p.gx, by = (lb / p.gx) % p.gy, z = lb / (p.gx * p.gy);
    const float* in = (const float*)p.a + (long)z * K * N;
    u16* out = (u16*)p.c + (long)z * K * N;
    int n0 = bx * 32, k0 = by * 32;
    int tx = tid & 31, ty = tid >> 5;
    for (int j = 0; j < 32; j += 8)
      ls[(ty + j) * 33 + tx] = in[(long)(k0 + ty + j) * N + n0 + tx];
    __syncthreads();
    int nr = tid >> 3, k4 = (tid & 7) * 4;
    ushort4 o;
    o.x = to_bf16(ls[(k4 + 0) * 33 + nr]);
    o.y = to_bf16(ls[(k4 + 1) * 33 + nr]);
    o.z = to_bf16(ls[(k4 + 2) * 33 + nr]);
    o.w = to_bf16(ls[(k4 + 3) * 33 + nr]);
    *(ushort4*)(out + (long)(n0 + nr) * K + k0 + k4) = o;
  } else if (p.mode == 2) {   // conv weight pack: [o][d][r] -> [o][r*512+d]
    int z = lb >> 9, oc = lb & 511;
    const float* src = (const float*)p.a + (long)z * 1048576 + oc * 2048;
    float4 va = *(const float4*)(src + tid * 8);
    float4 vb = *(const float4*)(src + tid * 8 + 4);
    int d0 = tid * 2;
    ls[d0] = va.x; ls[512 + d0] = va.y; ls[1024 + d0] = va.z; ls[1536 + d0] = va.w;
    ls[d0 + 1] = vb.x; ls[512 + d0 + 1] = vb.y; ls[1024 + d0 + 1] = vb.z; ls[1536 + d0 + 1] = vb.w;
    __syncthreads();
    int r2 = tid >> 6, dd = (tid & 63) * 8;
    union { u16 s[8]; uint4 u; } uo;
#pragma unroll
    for (int j = 0; j < 8; ++j) uo.s[j] = to_bf16(ls[r2 * 512 + dd + j]);
    *(uint4*)((u16*)p.c + (long)z * 1048576 + oc * 2048 + r2 * 512 + dd) = uo.u;
  } else if (p.mode == 3) {   // fp32 -> bf16 cvt, 8/thread
    int i = (lb * 256 + tid) * 8;
    if (i < p.p0) {
      float4 v0 = *(const float4*)((const float*)p.a + i);
      float4 v1 = *(const float4*)((const float*)p.a + i + 4);
      union { u16 s[8]; uint4 u; } uo;
      uo.s[0] = to_bf16(v0.x); uo.s[1] = to_bf16(v0.y);
      uo.s[2] = to_bf16(v0.z); uo.s[3] = to_bf16(v0.w);
      uo.s[4] = to_bf16(v1.x); uo.s[5] = to_bf16(v1.y);
      uo.s[6] = to_bf16(v1.z); uo.s[7] = to_bf16(v1.w);
      *(uint4*)((u16*)p.c + i) = uo.u;
    }
  } else {                    // mode 5: zero fill (uint4 units, p0 = count)
    int i = lb * 256 + tid;
    if (i < p.p0) { uint4 z4 = {0, 0, 0, 0}; ((uint4*)p.c)[i] = z4; }
  }
}

__global__ __launch_bounds__(64) void finloss_k(const float* __restrict__ loss,
                                                float* __restrict__ out) {
  if (threadIdx.x == 0) out[1048576] = loss[0] * (1.f / (1048576.f * 4.f));
}

extern "C" void kernel_launch(void* const* d_in, const int* in_sizes, int n_in,
                              void* d_out, int out_size, void* d_ws, size_t ws_size,
                              hipStream_t stream) {
  (void)in_sizes; (void)n_in; (void)out_size;
  const int* trg = (const int*)d_in[0];
  const float* latent = (const float*)d_in[3];
  const float* mems = (const float*)d_in[4];
  const float* cmems = (const float*)d_in[5];
  const float* pos_emb = (const float*)d_in[6];
  const float* embed = (const float*)d_in[7];
  const float* W_self = (const float*)d_in[8];
  const float* ln1_g = (const float*)d_in[9];
  const float* ln1_b = (const float*)d_in[10];
  const float* conv_w = (const float*)d_in[11];
  const float* conv_b = (const float*)d_in[12];
  const float* W_src = (const float*)d_in[13];
  const float* ln2_g = (const float*)d_in[14];
  const float* ln2_b = (const float*)d_in[15];
  const float* w1 = (const float*)d_in[16];
  const float* b1 = (const float*)d_in[17];
  const float* w2 = (const float*)d_in[18];
  const float* b2 = (const float*)d_in[19];

  float* ws = (float*)d_ws;
  long off = 0;
  auto alloc = [&](long n) { float* p = ws + off; off += (n + 63) & ~63L; return p; };
  float* x    = alloc(1048576);
  float* t0   = alloc(1048576);
  float* t1   = alloc(1048576);
  float* ocm  = alloc(1048576);
  float* Opart= alloc(3145728);       // 3 splits (self-attn nsplit=3)
  float* mlb  = alloc(98304);         // [3][2048][8][2]
  float* Opart2 = alloc(2097152);     // cross partials; h1 aliases (disjoint liveness)
  u16* h1   = (u16*)Opart2;           // [2048][2048] bf16, written AFTER crossout reads Opart2
  float* mlb2 = alloc(65536);
  u16* qb   = (u16*)alloc(524288);
  u16* qc   = (u16*)alloc(524288);
  u16* xh   = (u16*)alloc(262144);    // bf16 copy of layer input x
  u16* kbuf = (u16*)alloc(1179648);   // [4b][1152][512]: [cmem|mem|x] segments
  u16* vbuf = (u16*)alloc(1179648);   // [4b][512 d][1152 kv] transposed
  u16* kcm4 = (u16*)alloc(524288);    // all 4 layers
  u16* vcm4 = (u16*)alloc(524288);
  u16* klat4= (u16*)alloc(1048576);   // [4l][1024][512]
  u16* vlat4= (u16*)alloc(1048576);   // [4l][512][1024] transposed
  u16* ncm4h= (u16*)alloc(524288);    // [4l][512][512] bf16 (conv out, bias fused)
  u16* memh = (u16*)alloc(2097152);   // bf16 mems
  u16* cmemh= (u16*)alloc(524288);    // bf16 cmems
  u16* lath = (u16*)alloc(262144);    // bf16 latent
  u16* SQP  = (u16*)alloc(9437184);   // [4][8][512][1152] bf16 pre-shifted, *8 folded
  u16* wts  = (u16*)alloc(2097152);
  u16* wsr  = (u16*)alloc(2097152);
  u16* w1t  = (u16*)alloc(2097152);
  u16* w2t  = (u16*)alloc(2097152);
  u16* cwt  = (u16*)alloc(2097152);
  u16* post = (u16*)alloc(294912);
  float* lossacc = alloc(64);
  if ((size_t)off * 4 > ws_size) return;

  // ===== one-shot prep launch =====
  PrepBatch PB; PB.np = 0; int ptot = 0;
  auto padd = [&](int mode, const void* a, const void* b, void* c, void* d,
                  int p0, int p1, int gx, int gy, int blocks) {
    PrepArgs pa; pa.a = a; pa.b = b; pa.c = c; pa.d = d; pa.mode = mode;
    pa.p0 = p0; pa.p1 = p1; pa.gx = gx; pa.gy = gy;
    PB.p[PB.np] = pa; ptot += blocks; PB.end[PB.np] = ptot; PB.np++;
  };
  padd(0, embed, trg, x, xh, 0, 0, 0, 0, 1024);
  padd(1, W_self, nullptr, wts, nullptr, 512, 512, 16, 16, 4096);
  padd(1, W_src, nullptr, wsr, nullptr, 512, 512, 16, 16, 4096);
  padd(1, w1, nullptr, w1t, nullptr, 512, 2048, 64, 16, 4096);
  padd(1, w2, nullptr, w2t, nullptr, 2048, 512, 16, 64, 4096);
  padd(2, conv_w, nullptr, cwt, nullptr, 0, 0, 0, 0, 2048);
  padd(3, pos_emb, nullptr, post, nullptr, 589824, 0, 0, 0, 288);
  padd(3, mems, nullptr, memh, nullptr, 4194304, 0, 0, 0, 2048);
  padd(3, cmems, nullptr, cmemh, nullptr, 1048576, 0, 0, 0, 512);
  padd(3, latent, nullptr, lath, nullptr, 524288, 0, 0, 0, 256);
  padd(5, nullptr, nullptr, SQP, nullptr, 2359296, 0, 0, 0, 9216);
  padd(5, nullptr, nullptr, lossacc, nullptr, 1, 0, 0, 0, 1);
  prep_k<<<dim3(ptot), 256, 0, stream>>>(PB);

  auto ga = []() { GemmArgs g; g.alpha = 1.f; g.bias = nullptr; g.biasz = 0; g.res = nullptr;
                   g.ldres = 512; g.aml = nullptr; g.C2 = nullptr;
                   g.lng = nullptr; g.lnb = nullptr;
                   g.amode = 1; g.cmode = 0; g.act = 0; g.smode = 0; g.bdiv = 1; g.kparts = 1;
                   g.sA1 = g.sA2 = g.sB1 = g.sB2 = g.sC1 = g.sC2 = 0; g.N = 0;
                   g.gx = g.gy = 1; return g; };
  GemmBatch GB; GB.ng = 0; int gtot = 0;
  auto badd = [&](GemmArgs g, int gx, int gy, int gz) {
    g.gx = gx; g.gy = gy;
    GB.g[GB.ng] = g; gtot += gx * gy * gz; GB.end[GB.ng] = gtot; GB.ng++;
  };
  auto brun = [&]() {
    gemmb_k<<<dim3(gtot), 256, 0, stream>>>(GB);
    GB.ng = 0; gtot = 0;
  };
  auto run1 = [&](GemmArgs g, int gx, int gy, int gz) { badd(g, gx, gy, gz); brun(); };

  FBatch FB; FB.nf = 0; int ztot = 0;
  auto fadd = [&](const u16* Q, const u16* K, const u16* V, const u16* QP, void* O,
                  int L, int nsplit, long sKb, long sVb, int ldV, int obf16,
                  float* Op, float* ml) {
    FAttnArgs a; a.Q = Q; a.K = K; a.V = V; a.QP = QP; a.O = O;
    a.Opart = Op; a.ml = ml;
    a.L = L; a.nsplit = nsplit; a.sKb = sKb; a.sVb = sVb; a.ldV = ldV;
    a.scale = 0.125f; a.obf16 = obf16;
    FB.a[FB.nf] = a; ztot += 4 * nsplit; FB.zend[FB.nf] = ztot; FB.nf++;
  };
  auto frun = [&]() {
    fattnb_k<<<dim3(8, 8, ztot), 256, 0, stream>>>(FB);
    FB.nf = 0; ztot = 0;
  };

  // ===== batchA: all-layer mem/latent work {klat4, vlat4, conv->ncm4h} =====
  { GemmArgs g = ga(); g.A = lath; g.lda = 512; g.B = wsr + 262144; g.ldb = 512;
    g.sB1 = 1048576; g.C = klat4; g.ldc = 512; g.sC1 = 524288; g.cmode = 1; g.Kc = 512;
    badd(g, 8, 16, 4); }
  { GemmArgs g = ga(); g.A = lath; g.lda = 512; g.B = wsr + 2 * 262144; g.ldb = 512;
    g.sB1 = 1048576; g.C = vlat4; g.ldc = 1024; g.sC1 = 524288; g.cmode = 2; g.Kc = 512;
    badd(g, 8, 16, 4); }
  { GemmArgs g = ga(); g.A = memh; g.lda = 2048; g.sA1 = 1048576;
    g.B = cwt; g.ldb = 2048; g.sB1 = 1048576;
    g.C = ncm4h; g.ldc = 512; g.sC1 = 262144; g.cmode = 1;
    g.bias = conv_b; g.biasz = 512; g.Kc = 2048;
    badd(g, 8, 8, 4); }
  brun();

  for (int l = 0; l < 4; ++l) {
    const u16* Wt0 = wts + (l * 4 + 0) * 262144;
    const u16* Wt1 = wts + (l * 4 + 1) * 262144;
    const u16* Wt2 = wts + (l * 4 + 2) * 262144;
    const u16* Wt3 = wts + (l * 4 + 3) * 262144;
    const u16* Ws0 = wsr + (l * 4 + 0) * 262144;
    const u16* Ws3 = wsr + (l * 4 + 3) * 262144;
    const u16* memh_l = memh + (long)l * 1048576;
    const u16* cmemh_l = cmemh + (long)l * 262144;
    const u16* kcm_l = kcm4 + (long)l * 262144;
    const u16* vcm_l = vcm4 + (long)l * 262144;
    const u16* klat_l = klat4 + (long)l * 524288;
    const u16* vlat_l = vlat4 + (long)l * 524288;

    // ===== batchX: {qb, kbuf 3-seg, vbuf 3-seg} (+l0: kcm4, vcm4) =====
    { GemmArgs g = ga(); g.A = xh; g.lda = 512; g.B = Wt0; g.ldb = 512;
      g.C = qb; g.ldc = 512; g.cmode = 1; g.Kc = 512; badd(g, 8, 32, 1); }
    { GemmArgs g = ga(); g.A = cmemh_l; g.lda = 512; g.sA1 = 65536;
      g.B = Wt1; g.ldb = 512;
      g.C = kbuf; g.ldc = 512; g.sC1 = 589824; g.cmode = 1; g.Kc = 512; badd(g, 8, 2, 4); }
    { GemmArgs g = ga(); g.A = memh_l; g.lda = 512; g.sA1 = 262144;
      g.B = Wt1; g.ldb = 512;
      g.C = kbuf + 128 * 512; g.ldc = 512; g.sC1 = 589824; g.cmode = 1; g.Kc = 512;
      badd(g, 8, 8, 4); }
    { GemmArgs g = ga(); g.A = xh; g.lda = 512; g.sA1 = 262144;
      g.B = Wt1; g.ldb = 512;
      g.C = kbuf + 640 * 512; g.ldc = 512; g.sC1 = 589824; g.cmode = 1; g.Kc = 512;
      badd(g, 8, 8, 4); }
    { GemmArgs g = ga(); g.A = cmemh_l; g.lda = 512; g.sA1 = 65536;
      g.B = Wt2; g.ldb = 512;
      g.C = vbuf; g.ldc = 1152; g.sC1 = 589824; g.cmode = 2; g.Kc = 512; badd(g, 8, 2, 4); }
    { GemmArgs g = ga(); g.A = memh_l; g.lda = 512; g.sA1 = 262144;
      g.B = Wt2; g.ldb = 512;
      g.C = vbuf + 128; g.ldc = 1152; g.sC1 = 589824; g.cmode = 2; g.Kc = 512;
      badd(g, 8, 8, 4); }
    { GemmArgs g = ga(); g.A = xh; g.lda = 512; g.sA1 = 262144;
      g.B = Wt2; g.ldb = 512;
      g.C = vbuf + 640; g.ldc = 1152; g.sC1 = 589824; g.cmode = 2; g.Kc = 512;
      badd(g, 8, 8, 4); }
    if (l == 0) {
      { GemmArgs g = ga(); g.A = ncm4h; g.lda = 512; g.sA1 = 262144;
        g.B = wts + 262144; g.ldb = 512; g.sB1 = 1048576;
        g.C = kcm4; g.ldc = 512; g.sC1 = 262144; g.cmode = 1; g.Kc = 512; badd(g, 8, 8, 4); }
      { GemmArgs g = ga(); g.A = ncm4h; g.lda = 512; g.sA1 = 262144;
        g.B = wts + 2 * 262144; g.ldb = 512; g.sB1 = 1048576;
        g.C = vcm4; g.ldc = 512; g.sC1 = 262144; g.cmode = 2; g.Kc = 512; badd(g, 8, 8, 4); }
    }
    brun();

    // ===== batchS: SQP shifted scatter (depends on qb) =====
    { GemmArgs g = ga(); g.A = qb; g.lda = 512; g.sA1 = 262144; g.sA2 = 64;
      g.B = post; g.ldb = 64; g.sB1 = 0; g.sB2 = 73728;
      g.C = SQP; g.ldc = 1152; g.sC1 = 4718592; g.sC2 = 589824;
      g.smode = 1; g.alpha = 8.f; g.bdiv = 8; g.Kc = 64; run1(g, 18, 8, 32); }

    // ===== self-attention (nsplit=3; combine fused into attnout GEMM) =====
    fadd(qb, kbuf, vbuf, SQP, nullptr, 1152, 3, 589824, 589824, 1152, 1, Opart, mlb);
    frun();
    { GemmArgs g = ga(); g.A = Opart; g.amode = 2; g.N = 3; g.aml = mlb; g.lda = 512;
      g.sA1 = 1048576; g.B = Wt3; g.ldb = 512; g.C = t1; g.ldc = 512; g.res = x; g.Kc = 512;
      run1(g, 8, 32, 1); }

    // batchQ: {rattn Q, cross Q}, LN1 fused into A-staging (amode=3)
    { GemmArgs g = ga(); g.A = t1; g.amode = 3; g.lng = ln1_g + l * 512;
      g.lnb = ln1_b + l * 512; g.lda = 512; g.B = Wt0; g.ldb = 512;
      g.C = qb; g.ldc = 512; g.cmode = 1; g.Kc = 512; badd(g, 8, 32, 1); }
    { GemmArgs g = ga(); g.A = t1; g.amode = 3; g.lng = ln1_g + l * 512;
      g.lnb = ln1_b + l * 512; g.lda = 512; g.B = Ws0; g.ldb = 512;
      g.C = qc; g.ldc = 512; g.cmode = 1; g.Kc = 512; badd(g, 8, 32, 1); }
    brun();

    // ===== rattn (compression loss) + cross attention, one batched launch =====
    fadd(qb, kcm_l, vcm_l, nullptr, ocm, 128, 1, 65536, 128, 512, 0, Opart, mlb);
    fadd(qb, kbuf + 128 * 512, vbuf + 128, nullptr, nullptr, 512, 2, 589824, 589824, 1152, 0,
         Opart, mlb);
    fadd(qc, klat_l, vlat_l, nullptr, nullptr, 256, 2, 131072, 256, 1024, 1, Opart2, mlb2);
    frun();

    { GemmArgs g = ga(); g.A = Opart2; g.amode = 2; g.N = 2; g.aml = mlb2; g.lda = 512;
      g.sA1 = 1048576; g.B = Ws3; g.ldb = 512; g.C = t0; g.ldc = 512; g.Kc = 512;
      run1(g, 8, 32, 1); }

    // ===== FF1 (LN2 fused into A-staging) + loss in one launch =====
    { GemmArgs g = ga(); g.A = t0; g.amode = 3; g.lng = ln2_g + l * 512;
      g.lnb = ln2_b + l * 512; g.lda = 512; g.B = w1t + (long)l * 1048576;
      g.ldb = 512; g.C = h1; g.ldc = 2048; g.cmode = 1; g.bias = b1 + l * 2048; g.act = 1;
      g.Kc = 512; badd(g, 32, 32, 1); }
    { GemmArgs g = ga(); g.amode = 9; g.A = ocm; g.B = Opart; g.aml = mlb; g.C = lossacc;
      badd(g, 128, 1, 1); }
    brun();

    // ===== FF2: x = h1*w2 + b2 + t0, dual write fp32 (d_out on last layer) + bf16 xh
    { GemmArgs g = ga(); g.A = h1; g.lda = 2048;
      g.B = w2t + (long)l * 1048576; g.ldb = 2048;
      g.C = (l == 3) ? (float*)d_out : x; g.C2 = xh; g.ldc = 512; g.cmode = 4;
      g.bias = b2 + l * 512; g.res = t0; g.Kc = 2048;
      run1(g, 8, 32, 1); }
  }
  finloss_k<<<1, 64, 0, stream>>>(lossacc, (float*)d_out);
}

// Round 6
// 1058.564 us; speedup vs baseline: 1.2236x; 1.2236x over previous
//
#include <hip/hip_runtime.h>
#include <math.h>

typedef float floatx4 __attribute__((ext_vector_type(4)));
typedef __bf16 bf16x8 __attribute__((ext_vector_type(8)));
typedef unsigned short u16;

#define LDK 72  // LDS row stride in ushorts for fattn (144B, 16B-aligned)

__device__ inline u16 to_bf16(float f) {
  union { float f; unsigned u; } v; v.f = f;
  unsigned u = v.u;
  u += 0x7FFFu + ((u >> 16) & 1u);
  return (u16)(u >> 16);
}
__device__ inline float bf2f(u16 h) {
  union { unsigned u; float f; } v; v.u = ((unsigned)h) << 16; return v.f;
}

// async global->LDS, 16B per lane. LDS dest must be wave-uniform base
// (HW adds lane*16). Swizzled LDS content achieved by pre-swizzling the
// per-lane GLOBAL source address (rule #21: both-sides-or-neither).
__device__ inline void gload16(const void* g, void* l) {
  __builtin_amdgcn_global_load_lds(
      (const __attribute__((address_space(1))) unsigned int*)g,
      (__attribute__((address_space(3))) unsigned int*)l, 16, 0, 0);
}

struct GemmArgs {
  const void* A; const void* B; void* C; void* C2;
  int lda, ldb, ldc, N, Kc;   // N = nsplit for amode=2
  long sA1, sA2, sB1, sB2, sC1, sC2;
  float alpha;
  const float* bias; int biasz;   // bias index = col + zi*biasz
  const float* res; int ldres;
  const float* aml;  // amode=2/9: ml buffer [ns][2048][8][2]
  int amode;   // 1: A bf16, 2: A = flash-split combine, 9: loss
               // (R5 FAILED: LN-fused amode=3 raised VGPR 48->80, occupancy
               //  46%->23% for ALL gemm launches -- keep LN standalone)
  int cmode;   // 0: fp32 C, 1: bf16 C, 2: bf16 C transposed,
               // 4: dual write fp32 C + bf16 C2
  int act;     // exact gelu
  int smode;   // shifted bf16 scatter: C[row][col+row-511] = bf16(v) if >=0
  int bdiv, kparts;
  int gx, gy;  // grid decomposition of this descriptor's block range
};

#define MAXG 10
struct GemmBatch {
  GemmArgs g[MAXG];
  int end[MAXG];   // cumulative block-count ends
  int ng;
};

// Grouped GEMM, 64x64 tile, K-step 64 + loss descriptor mode.
// XCD chunk swizzle: consecutive LOGICAL blocks (which share A panels) are
// given to the SAME XCD (hw round-robins %8) -> A fetched ~once/XCD.
__global__ __launch_bounds__(256) void gemmb_k(GemmBatch gb) {
  int nwg = gridDim.x;
  int hw = blockIdx.x;
  int qn = nwg >> 3, rn = nwg & 7;
  int xcd = hw & 7, ii = hw >> 3;
  int bid = (xcd < rn ? xcd * (qn + 1) : rn * (qn + 1) + (xcd - rn) * qn) + ii;

  int gi = 0;
  while (bid >= gb.end[gi]) ++gi;
  const GemmArgs g = gb.g[gi];
  int lb = bid - (gi ? gb.end[gi - 1] : 0);
  int tid = threadIdx.x;

  if (g.amode == 9) {  // MSE loss with fused 2-way flash combine
    const float* oc = (const float*)g.A;
    const float* Op = (const float*)g.B;
    const float* ml = g.aml;
    float s = 0.f;
    for (long i = (long)lb * 256 + tid; i < 1048576; i += 256L * g.gx) {
      int row = (int)(i >> 9), col = (int)(i & 511), h = col >> 6;
      const float* mlp = ml + ((long)row * 8 + h) * 2;
      float m0v = mlp[0], l0v = mlp[1];
      float m1v = mlp[32768], l1v = mlp[32769];
      float mm = fmaxf(m0v, m1v);
      float w0 = __expf(m0v - mm), w1 = __expf(m1v - mm);
      float ov = (w0 * Op[i] + w1 * Op[1048576 + i]) / (w0 * l0v + w1 * l1v);
      float d = oc[i] - ov; s += d * d;
    }
    for (int o = 32; o > 0; o >>= 1) s += __shfl_xor(s, o, 64);
    __shared__ float red[4];
    if ((tid & 63) == 0) red[tid >> 6] = s;
    __syncthreads();
    if (tid == 0) atomicAdd((float*)g.C, red[0] + red[1] + red[2] + red[3]);
    return;
  }

  int bx = lb % g.gx;
  int rem = lb / g.gx;
  int by = rem % g.gy;
  int z = rem / g.gy;

  int kp = z % g.kparts;
  int zz = z / g.kparts;
  int zi = zz / g.bdiv, zj = zz % g.bdiv;
  long aoff = (long)zi * g.sA1 + (long)zj * g.sA2;
  long boff = (long)zi * g.sB1 + (long)zj * g.sB2;
  long coff = (long)zi * g.sC1 + (long)zj * g.sC2;
  const u16* Ah = (const u16*)g.A + aoff;
  const u16* Bh = (const u16*)g.B + boff;

  int m0 = by * 64, n0 = bx * 64;
  __shared__ u16 As[64][64];
  __shared__ u16 Bs[64][64];
  char* Asb = (char*)&As[0][0];
  char* Bsb = (char*)&Bs[0][0];
  int wave = tid >> 6, lane = tid & 63;
  int wr = (wave >> 1) * 32, wc = (wave & 1) * 32;
  int lr = lane & 15, qrow = lane >> 4;

  // async-staging geometry: lane covers LDS bytes o (linear); its global
  // source is the logical element whose swizzle lands at o.
  unsigned o0 = wave * 1024u + lane * 16u;
  unsigned o1 = o0 + 4096u;
  int ga_r0 = o0 >> 7, ga_r1 = o1 >> 7;
  int ga_c0 = (int)(o0 & 127u) ^ ((ga_r0 & 7) << 4);
  int ga_c1 = (int)(o1 & 127u) ^ ((ga_r1 & 7) << 4);
  long ldaB = (long)g.lda * 2, ldbB = (long)g.ldb * 2;
  // reg-staging geometry
  int r = tid >> 2, c16 = (tid & 3) << 4;
  int sw0 = (r << 7) + (((tid & 3) << 5) ^ ((r & 7) << 4));
  int sw1 = (r << 7) + ((((tid & 3) << 5) + 16) ^ ((r & 7) << 4));

  floatx4 acc[2][2];
#pragma unroll
  for (int i = 0; i < 2; ++i)
#pragma unroll
    for (int j = 0; j < 2; ++j)
#pragma unroll
      for (int rr = 0; rr < 4; ++rr) acc[i][j][rr] = 0.f;

  int kb0 = kp * g.Kc, kb1 = kb0 + g.Kc;
  for (int k0 = kb0; k0 < kb1; k0 += 64) {
    if (g.amode == 1) {
      const char* Ab = (const char*)Ah + ((long)m0 * g.lda + k0) * 2;
      gload16(Ab + ga_r0 * ldaB + ga_c0, Asb + wave * 1024);
      gload16(Ab + ga_r1 * ldaB + ga_c1, Asb + 4096 + wave * 1024);
    } else {  // amode 2: A = combine of g.N flash splits (ex-fcomb, fused)
      int row = m0 + r;
      int k = k0 + c16;               // all 16 cols in one head (k0%64==0)
      int ns = g.N;
      const float* mlp = g.aml + ((long)row * 8 + (k >> 6)) * 2;
      float mm = -1e30f;
#pragma unroll 3
      for (int s = 0; s < 3; ++s)
        if (s < ns) mm = fmaxf(mm, mlp[s * 32768]);
      float wgt[3]; float den = 0.f;
#pragma unroll 3
      for (int s = 0; s < 3; ++s)
        if (s < ns) { wgt[s] = __expf(mlp[s * 32768] - mm); den += wgt[s] * mlp[s * 32768 + 1]; }
      float inv = 1.f / den;
      float a16[16];
#pragma unroll
      for (int j = 0; j < 16; ++j) a16[j] = 0.f;
      const float* p0 = (const float*)g.A + (long)row * g.lda + k;
#pragma unroll 3
      for (int s = 0; s < 3; ++s)
        if (s < ns) {
          float w = wgt[s] * inv;
          const float* p = p0 + (long)s * g.sA1;
#pragma unroll
          for (int j = 0; j < 4; ++j) {
            float4 xx = *(const float4*)(p + j * 4);
            a16[j * 4 + 0] += w * xx.x; a16[j * 4 + 1] += w * xx.y;
            a16[j * 4 + 2] += w * xx.z; a16[j * 4 + 3] += w * xx.w;
          }
        }
      union { u16 s[8]; uint4 v; } u0, u1;
#pragma unroll
      for (int j = 0; j < 8; ++j) u0.s[j] = to_bf16(a16[j]);
#pragma unroll
      for (int j = 0; j < 8; ++j) u1.s[j] = to_bf16(a16[8 + j]);
      *(uint4*)(Asb + sw0) = u0.v; *(uint4*)(Asb + sw1) = u1.v;
    }
    {
      const char* Bb = (const char*)Bh + ((long)n0 * g.ldb + k0) * 2;
      gload16(Bb + ga_r0 * ldbB + ga_c0, Bsb + wave * 1024);
      gload16(Bb + ga_r1 * ldbB + ga_c1, Bsb + 4096 + wave * 1024);
    }
    __syncthreads();   // drains vmcnt (gload) + lgkm (ds_write)
#pragma unroll
    for (int ks = 0; ks < 2; ++ks) {
      int xk = ((ks * 32 + qrow * 8) << 1) ^ ((lr & 7) << 4);
      int rA0 = wr + lr, rB0 = wc + lr;
      bf16x8 a0 = *(const bf16x8*)(Asb + (rA0 << 7) + xk);
      bf16x8 a1 = *(const bf16x8*)(Asb + ((rA0 + 16) << 7) + xk);
      bf16x8 b0 = *(const bf16x8*)(Bsb + (rB0 << 7) + xk);
      bf16x8 b1 = *(const bf16x8*)(Bsb + ((rB0 + 16) << 7) + xk);
      acc[0][0] = __builtin_amdgcn_mfma_f32_16x16x32_bf16(a0, b0, acc[0][0], 0, 0, 0);
      acc[0][1] = __builtin_amdgcn_mfma_f32_16x16x32_bf16(a0, b1, acc[0][1], 0, 0, 0);
      acc[1][0] = __builtin_amdgcn_mfma_f32_16x16x32_bf16(a1, b0, acc[1][0], 0, 0, 0);
      acc[1][1] = __builtin_amdgcn_mfma_f32_16x16x32_bf16(a1, b1, acc[1][1], 0, 0, 0);
    }
    __syncthreads();
  }

#pragma unroll
  for (int mt = 0; mt < 2; ++mt)
#pragma unroll
    for (int nt = 0; nt < 2; ++nt) {
      int row0 = m0 + wr + mt * 16 + qrow * 4;
      int col = n0 + wc + nt * 16 + lr;
      if (g.cmode == 2) {
        ushort4 o;
        o.x = to_bf16(acc[mt][nt][0] * g.alpha);
        o.y = to_bf16(acc[mt][nt][1] * g.alpha);
        o.z = to_bf16(acc[mt][nt][2] * g.alpha);
        o.w = to_bf16(acc[mt][nt][3] * g.alpha);
        *(ushort4*)((u16*)g.C + coff + (long)col * g.ldc + row0) = o;
      } else {
#pragma unroll
        for (int rr = 0; rr < 4; ++rr) {
          int row = row0 + rr;
          float v = acc[mt][nt][rr] * g.alpha;
          if (g.smode) {
            int oc = col + row - 511;
            if (oc >= 0) ((u16*)g.C + coff)[(long)row * g.ldc + oc] = to_bf16(v);
          } else {
            if (g.bias) v += g.bias[col + zi * g.biasz];
            if (g.res) v += g.res[(long)row * g.ldres + col];
            if (g.act) v = 0.5f * v * (1.0f + erff(v * 0.70710678118654752f));
            if (g.cmode == 1) ((u16*)g.C + coff)[(long)row * g.ldc + col] = to_bf16(v);
            else if (g.cmode == 4) {
              ((float*)g.C + coff)[(long)row * g.ldc + col] = v;
              ((u16*)g.C2 + coff)[(long)row * g.ldc + col] = to_bf16(v);
            } else ((float*)g.C + coff)[(long)row * g.ldc + col] = v;
          }
        }
      }
    }
}

struct FAttnArgs {
  const u16* Q; const u16* K; const u16* V; const u16* QP;  // QP = pre-shifted SQP
  void* O; float* Opart; float* ml;
  int L, nsplit; long sKb, sVb; int ldV;
  float scale; int obf16;
};

struct FBatch {
  FAttnArgs a[3];
  int zend[3];  // cumulative z ends
  int nf;
};

// Fused flash attention, double-buffered K/V, optional pre-shifted pos bias,
// optional KV-split (unnormalized partials + m/l; combine fused in consumers).
__global__ __launch_bounds__(256) void fattnb_k(FBatch fb) {
  int zg = blockIdx.z;
  int fi = 0;
  while (zg >= fb.zend[fi]) ++fi;
  const FAttnArgs a = fb.a[fi];
  int zl = zg - (fi ? fb.zend[fi - 1] : 0);

  int qt = blockIdx.x, h = blockIdx.y;
  int b = zl / a.nsplit, sp = zl % a.nsplit;
  int Lc = a.L / a.nsplit, kt0 = sp * Lc, T = Lc >> 6;
  int tid = threadIdx.x, wave = tid >> 6, lane = tid & 63;
  int lr = lane & 15, quad = lane >> 4;
  __shared__ u16 Qs[64][LDK];
  __shared__ u16 Ks[2][64][LDK];
  __shared__ u16 Vs[2][64][LDK];
  __shared__ u16 Qp[4][16][LDK];
  __shared__ u16 Ps[4][16][LDK];
  int r = tid >> 2, c = (tid & 3) << 4;
  {
    const u16* qp = a.Q + (long)(b * 512 + qt * 64 + r) * 512 + h * 64 + c;
    *(uint4*)&Qs[r][c] = *(const uint4*)qp;
    *(uint4*)&Qs[r][c + 8] = *(const uint4*)(qp + 8);
  }
  const u16* Kb = a.K + (long)b * a.sKb + h * 64;
  const u16* Vb = a.V + (long)b * a.sVb + (long)(h * 64) * a.ldV;
  int qrow16 = lane >> 2, qc = (lane & 3) << 4;  // wave-private SQP tile loader
  const u16* QPr = a.QP ? a.QP + ((long)b * 8 + h) * 589824 +
                          (long)(qt * 64 + wave * 16 + qrow16) * 1152 : nullptr;
  // preload tile 0 straight into LDS buffer 0
  {
    const u16* kp = Kb + (long)(kt0 + r) * 512 + c;
    *(uint4*)&Ks[0][r][c] = *(const uint4*)kp;
    *(uint4*)&Ks[0][r][c + 8] = *(const uint4*)(kp + 8);
    const u16* vp = Vb + (long)r * a.ldV + kt0 + c;
    *(uint4*)&Vs[0][r][c] = *(const uint4*)vp;
    *(uint4*)&Vs[0][r][c + 8] = *(const uint4*)(vp + 8);
  }
  uint4 qpr0, qpr1;
  if (QPr) {  // 16 u16 per lane: two uint4s
    qpr0 = *(const uint4*)(QPr + kt0 + qc);
    qpr1 = *(const uint4*)(QPr + kt0 + qc + 8);
  }

  float m_run[4], l_run[4];
  floatx4 oacc[4];
#pragma unroll
  for (int i = 0; i < 4; ++i) {
    m_run[i] = -1e30f; l_run[i] = 0.f;
#pragma unroll
    for (int j = 0; j < 4; ++j) oacc[i][j] = 0.f;
  }

  for (int t = 0; t < T; ++t) {
    int cur = t & 1;
    bool more = (t + 1) < T;
    __syncthreads();
    uint4 pk0, pk1, pv0, pv1;
    if (more) {
      int kt = kt0 + (t + 1) * 64;
      const u16* kp = Kb + (long)(kt + r) * 512 + c;
      pk0 = *(const uint4*)kp; pk1 = *(const uint4*)(kp + 8);
      const u16* vp = Vb + (long)r * a.ldV + kt + c;
      pv0 = *(const uint4*)vp; pv1 = *(const uint4*)(vp + 8);
    }
    floatx4 sacc[4];
#pragma unroll
    for (int nt = 0; nt < 4; ++nt)
#pragma unroll
      for (int j = 0; j < 4; ++j) sacc[nt][j] = 0.f;
#pragma unroll
    for (int ks = 0; ks < 2; ++ks) {
      int kq = ks * 32 + quad * 8;
      bf16x8 av = *(const bf16x8*)&Qs[wave * 16 + lr][kq];
#pragma unroll
      for (int nt = 0; nt < 4; ++nt) {
        bf16x8 bb = *(const bf16x8*)&Ks[cur][nt * 16 + lr][kq];
        sacc[nt] = __builtin_amdgcn_mfma_f32_16x16x32_bf16(av, bb, sacc[nt], 0, 0, 0);
      }
    }
    if (QPr) {
      *(uint4*)&Qp[wave][qrow16][qc] = qpr0;
      *(uint4*)&Qp[wave][qrow16][qc + 8] = qpr1;
#pragma unroll
      for (int nt = 0; nt < 4; ++nt)
#pragma unroll
        for (int rr = 0; rr < 4; ++rr)
          sacc[nt][rr] = sacc[nt][rr] * a.scale + bf2f(Qp[wave][quad * 4 + rr][nt * 16 + lr]);
      if (more) {
        qpr0 = *(const uint4*)(QPr + kt0 + (t + 1) * 64 + qc);
        qpr1 = *(const uint4*)(QPr + kt0 + (t + 1) * 64 + qc + 8);
      }
    } else {
#pragma unroll
      for (int nt = 0; nt < 4; ++nt)
#pragma unroll
        for (int rr = 0; rr < 4; ++rr) sacc[nt][rr] *= a.scale;
    }
    // online softmax (rows replicated across the 16 lanes of a quad)
#pragma unroll
    for (int rr = 0; rr < 4; ++rr) {
      float m = -1e30f;
#pragma unroll
      for (int nt = 0; nt < 4; ++nt) m = fmaxf(m, sacc[nt][rr]);
      for (int o = 8; o > 0; o >>= 1) m = fmaxf(m, __shfl_xor(m, o, 64));
      float mn = fmaxf(m_run[rr], m);
      float al = __expf(m_run[rr] - mn);
      m_run[rr] = mn;
      float s = 0.f;
#pragma unroll
      for (int nt = 0; nt < 4; ++nt) {
        float p = __expf(sacc[nt][rr] - mn);
        sacc[nt][rr] = p;
        s += p;
      }
      for (int o = 8; o > 0; o >>= 1) s += __shfl_xor(s, o, 64);
      l_run[rr] = l_run[rr] * al + s;
#pragma unroll
      for (int nt = 0; nt < 4; ++nt) oacc[nt][rr] *= al;
    }
    // P (C-layout) -> LDS -> A-layout (wave-private)
#pragma unroll
    for (int nt = 0; nt < 4; ++nt) {
      Ps[wave][quad * 4 + 0][nt * 16 + lr] = to_bf16(sacc[nt][0]);
      Ps[wave][quad * 4 + 1][nt * 16 + lr] = to_bf16(sacc[nt][1]);
      Ps[wave][quad * 4 + 2][nt * 16 + lr] = to_bf16(sacc[nt][2]);
      Ps[wave][quad * 4 + 3][nt * 16 + lr] = to_bf16(sacc[nt][3]);
    }
#pragma unroll
    for (int ks = 0; ks < 2; ++ks) {
      int kq = ks * 32 + quad * 8;
      bf16x8 av = *(const bf16x8*)&Ps[wave][lr][kq];
#pragma unroll
      for (int nt = 0; nt < 4; ++nt) {
        bf16x8 bb = *(const bf16x8*)&Vs[cur][nt * 16 + lr][kq];
        oacc[nt] = __builtin_amdgcn_mfma_f32_16x16x32_bf16(av, bb, oacc[nt], 0, 0, 0);
      }
    }
    if (more) {  // stage prefetched tile into the other buffer
      *(uint4*)&Ks[cur ^ 1][r][c] = pk0; *(uint4*)&Ks[cur ^ 1][r][c + 8] = pk1;
      *(uint4*)&Vs[cur ^ 1][r][c] = pv0; *(uint4*)&Vs[cur ^ 1][r][c + 8] = pv1;
    }
  }
  if (a.nsplit == 1) {
    float inv[4];
#pragma unroll
    for (int rr = 0; rr < 4; ++rr) inv[rr] = 1.f / l_run[rr];
#pragma unroll
    for (int nt = 0; nt < 4; ++nt)
#pragma unroll
      for (int rr = 0; rr < 4; ++rr) {
        long row = b * 512 + qt * 64 + wave * 16 + quad * 4 + rr;
        float v = oacc[nt][rr] * inv[rr];
        if (a.obf16) ((u16*)a.O)[row * 512 + h * 64 + nt * 16 + lr] = to_bf16(v);
        else ((float*)a.O)[row * 512 + h * 64 + nt * 16 + lr] = v;
      }
  } else {
#pragma unroll
    for (int nt = 0; nt < 4; ++nt)
#pragma unroll
      for (int rr = 0; rr < 4; ++rr) {
        long row = b * 512 + qt * 64 + wave * 16 + quad * 4 + rr;
        a.Opart[((long)sp * 2048 + row) * 512 + h * 64 + nt * 16 + lr] = oacc[nt][rr];
      }
    if (lr == 0)
#pragma unroll
      for (int rr = 0; rr < 4; ++rr) {
        long row = b * 512 + qt * 64 + wave * 16 + quad * 4 + rr;
        long mi = (((long)sp * 2048 + row) * 8 + h) * 2;
        a.ml[mi] = m_run[rr]; a.ml[mi + 1] = l_run[rr];
      }
  }
}

// One-shot prep: embed (dual fp32+bf16), weight transposes, conv-w pack,
// fp32->bf16 cvts, zero-fills — vectorized, one launch.
struct PrepArgs { const void* a; const void* b; void* c; void* d; int mode, p0, p1, gx, gy; };
struct PrepBatch { PrepArgs p[12]; int end[12]; int np; };

__global__ __launch_bounds__(256) void prep_k(PrepBatch pb) {
  int bid = blockIdx.x, gi = 0;
  while (bid >= pb.end[gi]) ++gi;
  PrepArgs p = pb.p[gi];
  int lb = bid - (gi ? pb.end[gi - 1] : 0);
  int tid = threadIdx.x;
  __shared__ float ls[2048];
  if (p.mode == 0) {          // embed lookup, dual write fp32 + bf16, vec4
    int i = (lb * 256 + tid) * 4;
    int row = i >> 9, d = i & 511;
    float4 v = *(const float4*)((const float*)p.a +
                                (long)((const int*)p.b)[row] * 512 + d);
    *(float4*)((float*)p.c + i) = v;
    ushort4 h;
    h.x = to_bf16(v.x); h.y = to_bf16(v.y); h.z = to_bf16(v.z); h.w = to_bf16(v.w);
    *(ushort4*)((u16*)p.d + i) = h;
  } else if (p.mode == 1) {   // fp32 [K][N] -> bf16 [N][K] transpose, vec store
    int K = p.p0, N = p.p1;
    int bx = lb % p.gx, by = (lb / p.gx) % p.gy, z = lb / (p.gx * p.gy);
    const float* in = (const float*)p.a + (long)z * K * N;
    u16* out = (u16*)p.c + (long)z * K * N;
    int n0 = bx * 32, k0 = by * 32;
    int tx = tid & 31, ty = tid >> 5;
    for (int j = 0; j < 32; j += 8)
      ls[(ty + j) * 33 + tx] = in[(long)(k0 + ty + j) * N + n0 + tx];
    __syncthreads();
    int nr = tid >> 3, k4 = (tid & 7) * 4;
    ushort4 o;
    o.x = to_bf16(ls[(k4 + 0) * 33 + nr]);
    o.y = to_bf16(ls[(k4 + 1) * 33 + nr]);
    o.z = to_bf16(ls[(k4 + 2) * 33 + nr]);
    o.w = to_bf16(ls[(k4 + 3) * 33 + nr]);
    *(ushort4*)(out + (long)(n0 + nr) * K + k0 + k4) = o;
  } else if (p.mode == 2) {   // conv weight pack: [o][d][r] -> [o][r*512+d]
    int z = lb >> 9, oc = lb & 511;
    const float* src = (const float*)p.a + (long)z * 1048576 + oc * 2048;
    float4 va = *(const float4*)(src + tid * 8);
    float4 vb = *(const float4*)(src + tid * 8 + 4);
    int d0 = tid * 2;
    ls[d0] = va.x; ls[512 + d0] = va.y; ls[1024 + d0] = va.z; ls[1536 + d0] = va.w;
    ls[d0 + 1] = vb.x; ls[512 + d0 + 1] = vb.y; ls[1024 + d0 + 1] = vb.z; ls[1536 + d0 + 1] = vb.w;
    __syncthreads();
    int r2 = tid >> 6, dd = (tid & 63) * 8;
    union { u16 s[8]; uint4 u; } uo;
#pragma unroll
    for (int j = 0; j < 8; ++j) uo.s[j] = to_bf16(ls[r2 * 512 + dd + j]);
    *(uint4*)((u16*)p.c + (long)z * 1048576 + oc * 2048 + r2 * 512 + dd) = uo.u;
  } else if (p.mode == 3) {   // fp32 -> bf16 cvt, 8/thread
    int i = (lb * 256 + tid) * 8;
    if (i < p.p0) {
      float4 v0 = *(const float4*)((const float*)p.a + i);
      float4 v1 = *(const float4*)((const float*)p.a + i + 4);
      union { u16 s[8]; uint4 u; } uo;
      uo.s[0] = to_bf16(v0.x); uo.s[1] = to_bf16(v0.y);
      uo.s[2] = to_bf16(v0.z); uo.s[3] = to_bf16(v0.w);
      uo.s[4] = to_bf16(v1.x); uo.s[5] = to_bf16(v1.y);
      uo.s[6] = to_bf16(v1.z); uo.s[7] = to_bf16(v1.w);
      *(uint4*)((u16*)p.c + i) = uo.u;
    }
  } else {                    // mode 5: zero fill (uint4 units, p0 = count)
    int i = lb * 256 + tid;
    if (i < p.p0) { uint4 z4 = {0, 0, 0, 0}; ((uint4*)p.c)[i] = z4; }
  }
}

__global__ __launch_bounds__(256) void layernorm_k(const float* __restrict__ X,
                                                   const float* __restrict__ g,
                                                   const float* __restrict__ b,
                                                   u16* __restrict__ Y) {
  long row = blockIdx.x;
  const float* x = X + row * 512;
  int tid = threadIdx.x;
  float v0 = x[tid], v1 = x[tid + 256];
  __shared__ float red[256];
  red[tid] = v0 + v1; __syncthreads();
  for (int o = 128; o > 0; o >>= 1) { if (tid < o) red[tid] += red[tid + o]; __syncthreads(); }
  float mu = red[0] * (1.f / 512.f);
  __syncthreads();
  float d0 = v0 - mu, d1 = v1 - mu;
  red[tid] = d0 * d0 + d1 * d1; __syncthreads();
  for (int o = 128; o > 0; o >>= 1) { if (tid < o) red[tid] += red[tid + o]; __syncthreads(); }
  float rstd = rsqrtf(red[0] * (1.f / 512.f) + 1e-5f);
  Y[row * 512 + tid] = to_bf16(d0 * rstd * g[tid] + b[tid]);
  Y[row * 512 + tid + 256] = to_bf16(d1 * rstd * g[tid + 256] + b[tid + 256]);
}

__global__ __launch_bounds__(64) void finloss_k(const float* __restrict__ loss,
                                                float* __restrict__ out) {
  if (threadIdx.x == 0) out[1048576] = loss[0] * (1.f / (1048576.f * 4.f));
}

extern "C" void kernel_launch(void* const* d_in, const int* in_sizes, int n_in,
                              void* d_out, int out_size, void* d_ws, size_t ws_size,
                              hipStream_t stream) {
  (void)in_sizes; (void)n_in; (void)out_size;
  const int* trg = (const int*)d_in[0];
  const float* latent = (const float*)d_in[3];
  const float* mems = (const float*)d_in[4];
  const float* cmems = (const float*)d_in[5];
  const float* pos_emb = (const float*)d_in[6];
  const float* embed = (const float*)d_in[7];
  const float* W_self = (const float*)d_in[8];
  const float* ln1_g = (const float*)d_in[9];
  const float* ln1_b = (const float*)d_in[10];
  const float* conv_w = (const float*)d_in[11];
  const float* conv_b = (const float*)d_in[12];
  const float* W_src = (const float*)d_in[13];
  const float* ln2_g = (const float*)d_in[14];
  const float* ln2_b = (const float*)d_in[15];
  const float* w1 = (const float*)d_in[16];
  const float* b1 = (const float*)d_in[17];
  const float* w2 = (const float*)d_in[18];
  const float* b2 = (const float*)d_in[19];

  float* ws = (float*)d_ws;
  long off = 0;
  auto alloc = [&](long n) { float* p = ws + off; off += (n + 63) & ~63L; return p; };
  float* x    = alloc(1048576);
  float* t0   = alloc(1048576);
  float* t1   = alloc(1048576);
  float* ocm  = alloc(1048576);
  float* Opart= alloc(3145728);       // 3 splits (self-attn nsplit=3)
  float* mlb  = alloc(98304);         // [3][2048][8][2]
  float* Opart2 = alloc(2097152);     // cross partials; h1 aliases (disjoint liveness)
  u16* h1   = (u16*)Opart2;           // [2048][2048] bf16, written AFTER crossout reads Opart2
  float* mlb2 = alloc(65536);
  u16* qb   = (u16*)alloc(524288);
  u16* qc   = (u16*)alloc(524288);
  u16* xa   = (u16*)alloc(524288);
  u16* t1h  = (u16*)alloc(524288);
  u16* xh   = (u16*)alloc(262144);    // bf16 copy of layer input x
  u16* kbuf = (u16*)alloc(1179648);   // [4b][1152][512]: [cmem|mem|x] segments
  u16* vbuf = (u16*)alloc(1179648);   // [4b][512 d][1152 kv] transposed
  u16* kcm4 = (u16*)alloc(524288);    // all 4 layers
  u16* vcm4 = (u16*)alloc(524288);
  u16* klat4= (u16*)alloc(1048576);   // [4l][1024][512]
  u16* vlat4= (u16*)alloc(1048576);   // [4l][512][1024] transposed
  u16* ncm4h= (u16*)alloc(524288);    // [4l][512][512] bf16 (conv out, bias fused)
  u16* memh = (u16*)alloc(2097152);   // bf16 mems
  u16* cmemh= (u16*)alloc(524288);    // bf16 cmems
  u16* lath = (u16*)alloc(262144);    // bf16 latent
  u16* SQP  = (u16*)alloc(9437184);   // [4][8][512][1152] bf16 pre-shifted, *8 folded
  u16* wts  = (u16*)alloc(2097152);
  u16* wsr  = (u16*)alloc(2097152);
  u16* w1t  = (u16*)alloc(2097152);
  u16* w2t  = (u16*)alloc(2097152);
  u16* cwt  = (u16*)alloc(2097152);
  u16* post = (u16*)alloc(294912);
  float* lossacc = alloc(64);
  if ((size_t)off * 4 > ws_size) return;

  // ===== one-shot prep launch =====
  PrepBatch PB; PB.np = 0; int ptot = 0;
  auto padd = [&](int mode, const void* a, const void* b, void* c, void* d,
                  int p0, int p1, int gx, int gy, int blocks) {
    PrepArgs pa; pa.a = a; pa.b = b; pa.c = c; pa.d = d; pa.mode = mode;
    pa.p0 = p0; pa.p1 = p1; pa.gx = gx; pa.gy = gy;
    PB.p[PB.np] = pa; ptot += blocks; PB.end[PB.np] = ptot; PB.np++;
  };
  padd(0, embed, trg, x, xh, 0, 0, 0, 0, 1024);
  padd(1, W_self, nullptr, wts, nullptr, 512, 512, 16, 16, 4096);
  padd(1, W_src, nullptr, wsr, nullptr, 512, 512, 16, 16, 4096);
  padd(1, w1, nullptr, w1t, nullptr, 512, 2048, 64, 16, 4096);
  padd(1, w2, nullptr, w2t, nullptr, 2048, 512, 16, 64, 4096);
  padd(2, conv_w, nullptr, cwt, nullptr, 0, 0, 0, 0, 2048);
  padd(3, pos_emb, nullptr, post, nullptr, 589824, 0, 0, 0, 288);
  padd(3, mems, nullptr, memh, nullptr, 4194304, 0, 0, 0, 2048);
  padd(3, cmems, nullptr, cmemh, nullptr, 1048576, 0, 0, 0, 512);
  padd(3, latent, nullptr, lath, nullptr, 524288, 0, 0, 0, 256);
  padd(5, nullptr, nullptr, SQP, nullptr, 2359296, 0, 0, 0, 9216);
  padd(5, nullptr, nullptr, lossacc, nullptr, 1, 0, 0, 0, 1);
  prep_k<<<dim3(ptot), 256, 0, stream>>>(PB);

  auto ga = []() { GemmArgs g; g.alpha = 1.f; g.bias = nullptr; g.biasz = 0; g.res = nullptr;
                   g.ldres = 512; g.aml = nullptr; g.C2 = nullptr;
                   g.amode = 1; g.cmode = 0; g.act = 0; g.smode = 0; g.bdiv = 1; g.kparts = 1;
                   g.sA1 = g.sA2 = g.sB1 = g.sB2 = g.sC1 = g.sC2 = 0; g.N = 0;
                   g.gx = g.gy = 1; return g; };
  GemmBatch GB; GB.ng = 0; int gtot = 0;
  auto badd = [&](GemmArgs g, int gx, int gy, int gz) {
    g.gx = gx; g.gy = gy;
    GB.g[GB.ng] = g; gtot += gx * gy * gz; GB.end[GB.ng] = gtot; GB.ng++;
  };
  auto brun = [&]() {
    gemmb_k<<<dim3(gtot), 256, 0, stream>>>(GB);
    GB.ng = 0; gtot = 0;
  };
  auto run1 = [&](GemmArgs g, int gx, int gy, int gz) { badd(g, gx, gy, gz); brun(); };

  FBatch FB; FB.nf = 0; int ztot = 0;
  auto fadd = [&](const u16* Q, const u16* K, const u16* V, const u16* QP, void* O,
                  int L, int nsplit, long sKb, long sVb, int ldV, int obf16,
                  float* Op, float* ml) {
    FAttnArgs a; a.Q = Q; a.K = K; a.V = V; a.QP = QP; a.O = O;
    a.Opart = Op; a.ml = ml;
    a.L = L; a.nsplit = nsplit; a.sKb = sKb; a.sVb = sVb; a.ldV = ldV;
    a.scale = 0.125f; a.obf16 = obf16;
    FB.a[FB.nf] = a; ztot += 4 * nsplit; FB.zend[FB.nf] = ztot; FB.nf++;
  };
  auto frun = [&]() {
    fattnb_k<<<dim3(8, 8, ztot), 256, 0, stream>>>(FB);
    FB.nf = 0; ztot = 0;
  };

  // ===== batchA: all-layer mem/latent work {klat4, vlat4, conv->ncm4h} =====
  { GemmArgs g = ga(); g.A = lath; g.lda = 512; g.B = wsr + 262144; g.ldb = 512;
    g.sB1 = 1048576; g.C = klat4; g.ldc = 512; g.sC1 = 524288; g.cmode = 1; g.Kc = 512;
    badd(g, 8, 16, 4); }
  { GemmArgs g = ga(); g.A = lath; g.lda = 512; g.B = wsr + 2 * 262144; g.ldb = 512;
    g.sB1 = 1048576; g.C = vlat4; g.ldc = 1024; g.sC1 = 524288; g.cmode = 2; g.Kc = 512;
    badd(g, 8, 16, 4); }
  { GemmArgs g = ga(); g.A = memh; g.lda = 2048; g.sA1 = 1048576;
    g.B = cwt; g.ldb = 2048; g.sB1 = 1048576;
    g.C = ncm4h; g.ldc = 512; g.sC1 = 262144; g.cmode = 1;
    g.bias = conv_b; g.biasz = 512; g.Kc = 2048;
    badd(g, 8, 8, 4); }
  brun();

  for (int l = 0; l < 4; ++l) {
    const u16* Wt0 = wts + (l * 4 + 0) * 262144;
    const u16* Wt1 = wts + (l * 4 + 1) * 262144;
    const u16* Wt2 = wts + (l * 4 + 2) * 262144;
    const u16* Wt3 = wts + (l * 4 + 3) * 262144;
    const u16* Ws0 = wsr + (l * 4 + 0) * 262144;
    const u16* Ws3 = wsr + (l * 4 + 3) * 262144;
    const u16* memh_l = memh + (long)l * 1048576;
    const u16* cmemh_l = cmemh + (long)l * 262144;
    const u16* kcm_l = kcm4 + (long)l * 262144;
    const u16* vcm_l = vcm4 + (long)l * 262144;
    const u16* klat_l = klat4 + (long)l * 524288;
    const u16* vlat_l = vlat4 + (long)l * 524288;

    // ===== batchX: {qb, kbuf 3-seg, vbuf 3-seg} (+l0: kcm4, vcm4) =====
    { GemmArgs g = ga(); g.A = xh; g.lda = 512; g.B = Wt0; g.ldb = 512;
      g.C = qb; g.ldc = 512; g.cmode = 1; g.Kc = 512; badd(g, 8, 32, 1); }
    { GemmArgs g = ga(); g.A = cmemh_l; g.lda = 512; g.sA1 = 65536;
      g.B = Wt1; g.ldb = 512;
      g.C = kbuf; g.ldc = 512; g.sC1 = 589824; g.cmode = 1; g.Kc = 512; badd(g, 8, 2, 4); }
    { GemmArgs g = ga(); g.A = memh_l; g.lda = 512; g.sA1 = 262144;
      g.B = Wt1; g.ldb = 512;
      g.C = kbuf + 128 * 512; g.ldc = 512; g.sC1 = 589824; g.cmode = 1; g.Kc = 512;
      badd(g, 8, 8, 4); }
    { GemmArgs g = ga(); g.A = xh; g.lda = 512; g.sA1 = 262144;
      g.B = Wt1; g.ldb = 512;
      g.C = kbuf + 640 * 512; g.ldc = 512; g.sC1 = 589824; g.cmode = 1; g.Kc = 512;
      badd(g, 8, 8, 4); }
    { GemmArgs g = ga(); g.A = cmemh_l; g.lda = 512; g.sA1 = 65536;
      g.B = Wt2; g.ldb = 512;
      g.C = vbuf; g.ldc = 1152; g.sC1 = 589824; g.cmode = 2; g.Kc = 512; badd(g, 8, 2, 4); }
    { GemmArgs g = ga(); g.A = memh_l; g.lda = 512; g.sA1 = 262144;
      g.B = Wt2; g.ldb = 512;
      g.C = vbuf + 128; g.ldc = 1152; g.sC1 = 589824; g.cmode = 2; g.Kc = 512;
      badd(g, 8, 8, 4); }
    { GemmArgs g = ga(); g.A = xh; g.lda = 512; g.sA1 = 262144;
      g.B = Wt2; g.ldb = 512;
      g.C = vbuf + 640; g.ldc = 1152; g.sC1 = 589824; g.cmode = 2; g.Kc = 512;
      badd(g, 8, 8, 4); }
    if (l == 0) {
      { GemmArgs g = ga(); g.A = ncm4h; g.lda = 512; g.sA1 = 262144;
        g.B = wts + 262144; g.ldb = 512; g.sB1 = 1048576;
        g.C = kcm4; g.ldc = 512; g.sC1 = 262144; g.cmode = 1; g.Kc = 512; badd(g, 8, 8, 4); }
      { GemmArgs g = ga(); g.A = ncm4h; g.lda = 512; g.sA1 = 262144;
        g.B = wts + 2 * 262144; g.ldb = 512; g.sB1 = 1048576;
        g.C = vcm4; g.ldc = 512; g.sC1 = 262144; g.cmode = 2; g.Kc = 512; badd(g, 8, 8, 4); }
    }
    brun();

    // ===== batchS: SQP shifted scatter (depends on qb) =====
    { GemmArgs g = ga(); g.A = qb; g.lda = 512; g.sA1 = 262144; g.sA2 = 64;
      g.B = post; g.ldb = 64; g.sB1 = 0; g.sB2 = 73728;
      g.C = SQP; g.ldc = 1152; g.sC1 = 4718592; g.sC2 = 589824;
      g.smode = 1; g.alpha = 8.f; g.bdiv = 8; g.Kc = 64; run1(g, 18, 8, 32); }

    // ===== self-attention (nsplit=3; combine fused into attnout GEMM) =====
    fadd(qb, kbuf, vbuf, SQP, nullptr, 1152, 3, 589824, 589824, 1152, 1, Opart, mlb);
    frun();
    { GemmArgs g = ga(); g.A = Opart; g.amode = 2; g.N = 3; g.aml = mlb; g.lda = 512;
      g.sA1 = 1048576; g.B = Wt3; g.ldb = 512; g.C = t1; g.ldc = 512; g.res = x; g.Kc = 512;
      run1(g, 8, 32, 1); }
    layernorm_k<<<2048, 256, 0, stream>>>(t1, ln1_g + l * 512, ln1_b + l * 512, xa);

    // batchQ: {rattn Q, cross Q} (both from xa)
    { GemmArgs g = ga(); g.A = xa; g.lda = 512; g.B = Wt0; g.ldb = 512;
      g.C = qb; g.ldc = 512; g.cmode = 1; g.Kc = 512; badd(g, 8, 32, 1); }
    { GemmArgs g = ga(); g.A = xa; g.lda = 512; g.B = Ws0; g.ldb = 512;
      g.C = qc; g.ldc = 512; g.cmode = 1; g.Kc = 512; badd(g, 8, 32, 1); }
    brun();

    // ===== rattn (compression loss) + cross attention, one batched launch =====
    fadd(qb, kcm_l, vcm_l, nullptr, ocm, 128, 1, 65536, 128, 512, 0, Opart, mlb);
    fadd(qb, kbuf + 128 * 512, vbuf + 128, nullptr, nullptr, 512, 2, 589824, 589824, 1152, 0,
         Opart, mlb);
    fadd(qc, klat_l, vlat_l, nullptr, nullptr, 256, 2, 131072, 256, 1024, 1, Opart2, mlb2);
    frun();

    { GemmArgs g = ga(); g.A = Opart2; g.amode = 2; g.N = 2; g.aml = mlb2; g.lda = 512;
      g.sA1 = 1048576; g.B = Ws3; g.ldb = 512; g.C = t0; g.ldc = 512; g.Kc = 512;
      run1(g, 8, 32, 1); }
    layernorm_k<<<2048, 256, 0, stream>>>(t0, ln2_g + l * 512, ln2_b + l * 512, t1h);

    // ===== FF1 + loss in one launch =====
    { GemmArgs g = ga(); g.A = t1h; g.lda = 512; g.B = w1t + (long)l * 1048576;
      g.ldb = 512; g.C = h1; g.ldc = 2048; g.cmode = 1; g.bias = b1 + l * 2048; g.act = 1;
      g.Kc = 512; badd(g, 32, 32, 1); }
    { GemmArgs g = ga(); g.amode = 9; g.A = ocm; g.B = Opart; g.aml = mlb; g.C = lossacc;
      badd(g, 128, 1, 1); }
    brun();

    // ===== FF2: x = h1*w2 + b2 + t0, dual write fp32 (d_out on last layer) + bf16 xh
    { GemmArgs g = ga(); g.A = h1; g.lda = 2048;
      g.B = w2t + (long)l * 1048576; g.ldb = 2048;
      g.C = (l == 3) ? (float*)d_out : x; g.C2 = xh; g.ldc = 512; g.cmode = 4;
      g.bias = b2 + l * 512; g.res = t0; g.Kc = 2048;
      run1(g, 8, 32, 1); }
  }
  finloss_k<<<1, 64, 0, stream>>>(lossacc, (float*)d_out);
}